// Round 6
// baseline (345.191 us; speedup 1.0000x reference)
//
#include <hip/hip_runtime.h>
#include <hip/hip_bf16.h>

typedef __attribute__((ext_vector_type(8))) short short8;
typedef __attribute__((ext_vector_type(4))) short short4v;
typedef __attribute__((ext_vector_type(4))) float float4v;

#define LQN 2048
#define DM 1024

#define GAS __attribute__((address_space(1)))
#define LAS __attribute__((address_space(3)))

__device__ __forceinline__ short f2bf(float f) {
  unsigned u = __builtin_bit_cast(unsigned, f);
  u += 0x7fff + ((u >> 16) & 1);
  return (short)(u >> 16);
}

// PV matmul: 16x16x16 bf16 MFMA. Builtin probe device-side only (host pass
// can't see amdgcn builtins — R3 lesson).
__device__ __forceinline__ float4v mfma_pv(short4v a, short4v b, float4v c) {
#if defined(__HIP_DEVICE_COMPILE__)
#if __has_builtin(__builtin_amdgcn_mfma_f32_16x16x16_bf16)
  return __builtin_amdgcn_mfma_f32_16x16x16_bf16(a, b, c, 0, 0, 0);
#else
  return __builtin_amdgcn_mfma_f32_16x16x16bf16_1k(a, b, c, 0, 0, 0);
#endif
#else
  (void)a; (void)b;
  return c;
#endif
}

// ---------------------------------------------------------------------------
// Convert query/key f32 -> bf16 into d_out (free scratch until flash writes).
// ---------------------------------------------------------------------------
__global__ __launch_bounds__(256) void convert_qk(const float* __restrict__ q,
                                                  const float* __restrict__ k,
                                                  short* __restrict__ dst0)
{
  const float* src = blockIdx.y ? k : q;
  short* dst = dst0 + (size_t)blockIdx.y * 8388608;
  const size_t base = ((size_t)blockIdx.x * 256 + threadIdx.x) * 8;
  float4v a = *(const float4v*)&src[base];
  float4v b = *(const float4v*)&src[base + 4];
  short8 o8 = {f2bf(a.x), f2bf(a.y), f2bf(a.z), f2bf(a.w),
               f2bf(b.x), f2bf(b.y), f2bf(b.z), f2bf(b.w)};
  *(short8*)&dst[base] = o8;
}

// Convert Wq/Wk/Wv f32 -> bf16 into ws (enables async-LDS B staging)
__global__ __launch_bounds__(256) void convert_w(const float* __restrict__ Wq,
                                                 const float* __restrict__ Wk,
                                                 const float* __restrict__ Wv,
                                                 short* __restrict__ Wbf)
{
  const int z = blockIdx.y;
  const float* src = (z == 0) ? Wq : (z == 1) ? Wk : Wv;
  short* dst = Wbf + (size_t)z * 1048576;
  const size_t base = ((size_t)blockIdx.x * 256 + threadIdx.x) * 8;
  float4v a = *(const float4v*)&src[base];
  float4v b = *(const float4v*)&src[base + 4];
  short8 o8 = {f2bf(a.x), f2bf(a.y), f2bf(a.z), f2bf(a.w),
               f2bf(b.x), f2bf(b.y), f2bf(b.z), f2bf(b.w)};
  *(short8*)&dst[base] = o8;
}

// ---------------------------------------------------------------------------
// GEMM: out = A @ W^T. A bf16 (d_out staging). BK=64 as two 32-col planes
// (keeps the proven [row][32] LDS bank pattern AND async-LDS linearity);
// halves barrier count vs BK=32 at 32 KiB LDS. z=0: Q (scaled by
// log2e/32 so flash can use exp2), z=1: K, z=2: V stored transposed
// Vt[n][d][kpos].
// ---------------------------------------------------------------------------
template <bool WBF>
__global__ __launch_bounds__(256, 2) void gemm_qkv(
    const short* __restrict__ Abf, const float* __restrict__ Wq,
    const float* __restrict__ Wk, const float* __restrict__ Wv,
    const short* __restrict__ Wbf,
    short* __restrict__ Qbf, short* __restrict__ Kbf, short* __restrict__ Vt)
{
  __shared__ __align__(16) short As[2 * 4096];  // [plane(2)][128 rows][32]
  __shared__ __align__(16) short Bs[2 * 4096];

  const int z = blockIdx.z;
  const short* Ag = (z == 0) ? Abf : (Abf + 8388608);
  const float* Wg = (z == 0) ? Wq : (z == 1) ? Wk : Wv;
  const short* Wbz = WBF ? (Wbf + (size_t)z * 1048576) : nullptr;

  const int m0 = blockIdx.x * 128;
  const int n0 = blockIdx.y * 128;
  const int t = threadIdx.x;
  const int lane = t & 63;
  const int lrow = lane & 15;
  const int quad = lane >> 4;
  const int wave = t >> 6;
  const int wm = (wave & 1) * 64;
  const int wn = (wave >> 1) * 64;

  // staging indices: chunk (q*256+t) -> row = q*64 + (t>>2), col8 = (t&3)*8
  const int srow = t >> 2;
  const int scol8 = (t & 3) * 8;
  const int sldsb = (t & 192) * 8;  // wave-uniform; HW adds lane*16B

  float4v acc[4][4];
#pragma unroll
  for (int i = 0; i < 4; i++)
#pragma unroll
    for (int j = 0; j < 4; j++) acc[i][j] = (float4v){0.f, 0.f, 0.f, 0.f};

  for (int kk = 0; kk < 1024; kk += 64) {
    __syncthreads();
#pragma unroll
    for (int pl = 0; pl < 2; pl++) {
#pragma unroll
      for (int q = 0; q < 2; q++) {
        const int row = q * 64 + srow;
        const short* gp = &Ag[(size_t)(m0 + row) * DM + kk + pl * 32 + scol8];
        short* lp = &As[pl * 4096 + (q * 256 + (t & 192)) * 8];
        __builtin_amdgcn_global_load_lds((const GAS void*)gp, (LAS void*)lp, 16, 0, 0);
        if (WBF) {
          const short* gpb = &Wbz[(size_t)(n0 + row) * DM + kk + pl * 32 + scol8];
          short* lpb = &Bs[pl * 4096 + (q * 256 + (t & 192)) * 8];
          __builtin_amdgcn_global_load_lds((const GAS void*)gpb, (LAS void*)lpb, 16, 0, 0);
        }
      }
    }
    if (!WBF) {
#pragma unroll
      for (int p = 0; p < 4; p++) {
        const int row = p * 32 + (t >> 3);
#pragma unroll
        for (int cp = 0; cp < 2; cp++) {
          const int c4 = (t & 7) * 4;
          float4v b = *(const float4v*)&Wg[(size_t)(n0 + row) * DM + kk + cp * 32 + c4];
          short4v b16 = {f2bf(b.x), f2bf(b.y), f2bf(b.z), f2bf(b.w)};
          *(short4v*)&Bs[cp * 4096 + row * 32 + c4] = b16;
        }
      }
    }
    __syncthreads();

#pragma unroll
    for (int ko = 0; ko < 2; ko++) {
      short8 af[4], bf[4];
#pragma unroll
      for (int i = 0; i < 4; i++) {
        af[i] = *(const short8*)&As[ko * 4096 + (wm + i * 16 + lrow) * 32 + quad * 8];
        bf[i] = *(const short8*)&Bs[ko * 4096 + (wn + i * 16 + lrow) * 32 + quad * 8];
      }
#pragma unroll
      for (int i = 0; i < 4; i++)
#pragma unroll
        for (int j = 0; j < 4; j++)
          acc[i][j] = __builtin_amdgcn_mfma_f32_16x16x32_bf16(af[i], bf[j],
                                                              acc[i][j], 0, 0, 0);
    }
  }

  if (z < 2) {
    short* Og = (z == 0) ? Qbf : Kbf;
    // Q scale: 1/sqrt(D) * log2(e) so flash uses exp2 directly
    const float sc = (z == 0) ? 0.03125f * 1.44269504f : 1.0f;
#pragma unroll
    for (int i = 0; i < 4; i++)
#pragma unroll
      for (int j = 0; j < 4; j++)
#pragma unroll
        for (int r = 0; r < 4; r++) {
          const int row = m0 + wm + i * 16 + quad * 4 + r;
          const int col = n0 + wn + j * 16 + lrow;
          Og[(size_t)row * DM + col] = f2bf(acc[i][j][r] * sc);
        }
  } else {
#pragma unroll
    for (int i = 0; i < 4; i++) {
      const int rowb = m0 + wm + i * 16 + quad * 4;
      const int batch = rowb >> 11;
      const int kpos = rowb & 2047;
#pragma unroll
      for (int j = 0; j < 4; j++) {
        const int col = n0 + wn + j * 16 + lrow;
        short4v pk = {f2bf(acc[i][j][0]), f2bf(acc[i][j][1]),
                      f2bf(acc[i][j][2]), f2bf(acc[i][j][3])};
        *(short4v*)&Vt[(size_t)batch * DM * LQN + (size_t)col * LQN + kpos] = pk;
      }
    }
  }
}

// ---------------------------------------------------------------------------
// Flash attention R6: R5 hybrid + LOAD BALANCING.
// Block processes q-tile pair (a, 15-a) sequentially: (2a+2)+(2(15-a)+2)=34
// k-iterations, UNIFORM across all 512 blocks (2/CU, perfectly balanced).
// Per tile: 4 waves x 32 q-rows, 64-key double-buffered LDS tiles (K async
// global_load_lds, V reg-load-early/ds_write-late), one barrier/iter,
// S^T = K*Q^T keeps P in registers. exp2 (scale folded into Q).
// LDS cross-half hazard-free: nkt even => last iter reads buf 1, next
// prologue writes buf 0, and all waves already passed the last barrier.
// ---------------------------------------------------------------------------
__global__ __launch_bounds__(256, 4) void flash_attn(
    const short* __restrict__ Qbf, const short* __restrict__ Kbf,
    const short* __restrict__ Vt, const float* __restrict__ query,
    float* __restrict__ res)
{
  __shared__ __align__(16) short Ks[2][4096];     // [dh(2)][key(64)][32 d]
  __shared__ __align__(16) short Vs[2][64 * 76];  // [d(64)][76: 64 keys+pad]

  const int b = blockIdx.x;                    // 512 blocks
  const int nh = (b & 7) | ((b >> 6) << 3);    // b%8 fixed per nh-group -> XCD
  const int pair = (b >> 3) & 7;               // 0..7
  const int h = nh & 15;
  const int n = nh >> 4;
  const int t = threadIdx.x;
  const int lane = t & 63;
  const int wave = t >> 6;
  const int lrow = lane & 15;
  const int quad = lane >> 4;

  const size_t rowoff = (size_t)n * LQN;
  const size_t hcol = (size_t)h * 64;
  const size_t vtoff = (size_t)n * (size_t)DM * LQN + hcol * LQN;

  // staging indices
  const int skey = t >> 2;            // K: key row / V: d row
  const int sq8 = (t & 3) * 8;        // K: d-offset
  const int skq = (t & 3) * 16;       // V: key-offset
  const int ldsbase = (t & 192) * 8;  // wave-uniform (HW adds lane*16B)

#pragma unroll
  for (int half = 0; half < 2; half++) {
    const int qt = half ? (15 - pair) : pair;  // uniform per block
    const int qb = qt * 128;
    const int wrow = qb + wave * 32;

    // Q fragments [mt][dhalf] (B-operand of S^T)
    short8 qf[2][2];
#pragma unroll
    for (int mt = 0; mt < 2; mt++)
#pragma unroll
      for (int dh = 0; dh < 2; dh++)
        qf[mt][dh] = *(const short8*)
            &Qbf[(rowoff + wrow + mt * 16 + lrow) * DM + hcol + dh * 32 + quad * 8];

    float4v o[2][4];
#pragma unroll
    for (int mt = 0; mt < 2; mt++)
#pragma unroll
      for (int j = 0; j < 4; j++) o[mt][j] = (float4v){0.f, 0.f, 0.f, 0.f};
    float lsum[2] = {0.f, 0.f};

    const int nkt = 2 * qt + 2;  // even

    // prologue: stage tile 0
    {
      const short* g0 = &Kbf[(rowoff + skey) * DM + hcol + sq8];
      __builtin_amdgcn_global_load_lds((const GAS void*)g0,
                                       (LAS void*)&Ks[0][ldsbase], 16, 0, 0);
      const short* g1 = &Kbf[(rowoff + skey) * DM + hcol + 32 + sq8];
      __builtin_amdgcn_global_load_lds((const GAS void*)g1,
                                       (LAS void*)&Ks[0][2048 + ldsbase], 16, 0, 0);
      const short* gv = &Vt[vtoff + (size_t)skey * LQN + skq];
      short4v v0 = *(const short4v*)(gv);
      short4v v1 = *(const short4v*)(gv + 4);
      short4v v2 = *(const short4v*)(gv + 8);
      short4v v3 = *(const short4v*)(gv + 12);
      short* l = &Vs[0][skey * 76 + skq];
      *(short4v*)(l + 0) = v0;
      *(short4v*)(l + 4) = v1;
      *(short4v*)(l + 8) = v2;
      *(short4v*)(l + 12) = v3;
    }

    for (int kt = 0; kt < nkt; kt++) {
      __syncthreads();  // drains async K + makes V writes visible
      const int buf = kt & 1;
      const int nbuf = buf ^ 1;
      const int kbase = kt * 64;
      const bool more = (kt + 1 < nkt);

      short4v v0, v1, v2, v3;
      if (more) {  // issue next tile's loads NOW
        const int kb2 = kbase + 64;
        const short* g0 = &Kbf[(rowoff + kb2 + skey) * DM + hcol + sq8];
        __builtin_amdgcn_global_load_lds((const GAS void*)g0,
                                         (LAS void*)&Ks[nbuf][ldsbase], 16, 0, 0);
        const short* g1 = &Kbf[(rowoff + kb2 + skey) * DM + hcol + 32 + sq8];
        __builtin_amdgcn_global_load_lds((const GAS void*)g1,
                                         (LAS void*)&Ks[nbuf][2048 + ldsbase], 16, 0, 0);
        const short* gv = &Vt[vtoff + (size_t)skey * LQN + kb2 + skq];
        v0 = *(const short4v*)(gv);
        v1 = *(const short4v*)(gv + 4);
        v2 = *(const short4v*)(gv + 8);
        v3 = *(const short4v*)(gv + 12);
      }

      const int drel = wrow - kbase;
#pragma unroll
      for (int f4 = 0; f4 < 4; f4++) {
        if (f4 * 16 > drel + 31) continue;  // fully masked both mt (uniform)
        short8 kf0 = *(const short8*)&Ks[buf][(f4 * 16 + lrow) * 32 + quad * 8];
        short8 kf1 = *(const short8*)&Ks[buf][2048 + (f4 * 16 + lrow) * 32 + quad * 8];
        short4v vf[4];
#pragma unroll
        for (int j = 0; j < 4; j++)
          vf[j] = *(const short4v*)&Vs[buf][(j * 16 + lrow) * 76 + f4 * 16 + quad * 4];
#pragma unroll
        for (int mt = 0; mt < 2; mt++) {
          if (f4 * 16 > drel + mt * 16 + 15) continue;  // fully masked (uniform)
          float4v z = (float4v){0.f, 0.f, 0.f, 0.f};
          z = __builtin_amdgcn_mfma_f32_16x16x32_bf16(kf0, qf[mt][0], z, 0, 0, 0);
          z = __builtin_amdgcn_mfma_f32_16x16x32_bf16(kf1, qf[mt][1], z, 0, 0, 0);
          const bool pm = (f4 * 16 + 15 > drel + mt * 16);  // partial mask?
          const int dk = drel + mt * 16 + lrow;
          short4v pk;
          float ls = 0.f;
#pragma unroll
          for (int r = 0; r < 4; r++) {
            float p = exp2f(z[r]);  // log2e/32 folded into Q; |s| small, no max
            if (pm && (f4 * 16 + quad * 4 + r > dk)) p = 0.f;
            ls += p;
            pk[r] = f2bf(p);
          }
          lsum[mt] += ls;
#pragma unroll
          for (int j = 0; j < 4; j++)
            o[mt][j] = mfma_pv(pk, vf[j], o[mt][j]);
        }
      }

      if (more) {  // ds_write AFTER compute: vmcnt wait lands post-compute
        short* l = &Vs[nbuf][skey * 76 + skq];
        *(short4v*)(l + 0) = v0;
        *(short4v*)(l + 4) = v1;
        *(short4v*)(l + 8) = v2;
        *(short4v*)(l + 12) = v3;
      }
    }

    // column sums: reduce across quads, then fetch per-C/D-row inverse
    float inv[2][4];
#pragma unroll
    for (int mt = 0; mt < 2; mt++) {
      float s = lsum[mt];
      s += __shfl_xor(s, 16);
      s += __shfl_xor(s, 32);
#pragma unroll
      for (int r = 0; r < 4; r++) inv[mt][r] = 1.0f / __shfl(s, quad * 4 + r);
    }

    // res = O/l + query
#pragma unroll
    for (int mt = 0; mt < 2; mt++)
#pragma unroll
      for (int r = 0; r < 4; r++) {
        const size_t row = rowoff + wrow + mt * 16 + quad * 4 + r;
#pragma unroll
        for (int j = 0; j < 4; j++) {
          const size_t idx = row * DM + hcol + j * 16 + lrow;
          res[idx] = o[mt][j][r] * inv[mt][r] + query[idx];
        }
      }
  }
}

// ---------------------------------------------------------------------------
// BatchNorm over (8192, 1024)
// ---------------------------------------------------------------------------
__global__ __launch_bounds__(256) void bn_stats(const float* __restrict__ res,
                                                float* __restrict__ stats)
{
  const int t = threadIdx.x;
  const int b = blockIdx.x;  // 512 blocks x 16 rows
  float4v sum = (float4v){0.f, 0.f, 0.f, 0.f};
  float4v sq = (float4v){0.f, 0.f, 0.f, 0.f};
  for (int r = 0; r < 16; r++) {
    float4v v = *(const float4v*)&res[(size_t)(b * 16 + r) * DM + t * 4];
    sum += v;
    sq += v * v;
  }
#pragma unroll
  for (int i = 0; i < 4; i++) {
    atomicAdd(&stats[t * 4 + i], sum[i]);
    atomicAdd(&stats[1024 + t * 4 + i], sq[i]);
  }
}

__global__ __launch_bounds__(256) void bn_apply(float* __restrict__ res,
                                                const float* __restrict__ stats,
                                                const float* __restrict__ gamma,
                                                const float* __restrict__ beta)
{
  const size_t i = (size_t)blockIdx.x * 256 + threadIdx.x;
  const int c = (int)(i & 255) * 4;
  float4v v = *(const float4v*)&res[i * 4];
  float4v sm = *(const float4v*)&stats[c];
  float4v sq = *(const float4v*)&stats[1024 + c];
  float4v g = *(const float4v*)&gamma[c];
  float4v bt = *(const float4v*)&beta[c];
  float4v outv;
#pragma unroll
  for (int j = 0; j < 4; j++) {
    const float mean = sm[j] * (1.0f / 8192.0f);
    const float var = sq[j] * (1.0f / 8192.0f) - mean * mean;
    outv[j] = (v[j] - mean) * rsqrtf(var + 1e-5f) * g[j] + bt[j];
  }
  *(float4v*)&res[i * 4] = outv;
}

// ---------------------------------------------------------------------------
extern "C" void kernel_launch(void* const* d_in, const int* in_sizes, int n_in,
                              void* d_out, int out_size, void* d_ws,
                              size_t ws_size, hipStream_t stream)
{
  const float* query = (const float*)d_in[0];
  const float* key   = (const float*)d_in[1];
  const float* Wq    = (const float*)d_in[2];
  const float* Wk    = (const float*)d_in[3];
  const float* Wv    = (const float*)d_in[4];
  const float* gamma = (const float*)d_in[5];
  const float* beta  = (const float*)d_in[6];
  float* out = (float*)d_out;

  char* ws = (char*)d_ws;
  short* Qbf = (short*)(ws);                               // 16 MiB
  short* Kbf = (short*)(ws + (size_t)16 * 1024 * 1024);    // 16 MiB
  short* Vt  = (short*)(ws + (size_t)32 * 1024 * 1024);    // 16 MiB (V^T)
  float* stats = (float*)(ws + (size_t)48 * 1024 * 1024);  // 8 KiB
  short* Wbf = (short*)(ws + (size_t)49 * 1024 * 1024);    // 6 MiB (optional)
  const bool wbf = ws_size >= ((size_t)55 << 20);

  (void)hipMemsetAsync(stats, 0, 2048 * sizeof(float), stream);

  convert_qk<<<dim3(4096, 2), 256, 0, stream>>>(query, key, (short*)d_out);
  if (wbf) {
    convert_w<<<dim3(512, 3), 256, 0, stream>>>(Wq, Wk, Wv, Wbf);
    gemm_qkv<true><<<dim3(64, 8, 3), 256, 0, stream>>>(
        (const short*)d_out, Wq, Wk, Wv, Wbf, Qbf, Kbf, Vt);
  } else {
    gemm_qkv<false><<<dim3(64, 8, 3), 256, 0, stream>>>(
        (const short*)d_out, Wq, Wk, Wv, nullptr, Qbf, Kbf, Vt);
  }
  flash_attn<<<dim3(512), 256, 0, stream>>>(Qbf, Kbf, Vt, query, out);
  bn_stats<<<dim3(512), 256, 0, stream>>>(out, stats);
  bn_apply<<<dim3(8192), 256, 0, stream>>>(out, stats, gamma, beta);
}

// Round 7
// 322.481 us; speedup vs baseline: 1.0704x; 1.0704x over previous
//
#include <hip/hip_runtime.h>
#include <hip/hip_bf16.h>

typedef __attribute__((ext_vector_type(8))) short short8;
typedef __attribute__((ext_vector_type(4))) short short4v;
typedef __attribute__((ext_vector_type(4))) float float4v;

#define LQN 2048
#define DM 1024

#define GAS __attribute__((address_space(1)))
#define LAS __attribute__((address_space(3)))

__device__ __forceinline__ short f2bf(float f) {
  unsigned u = __builtin_bit_cast(unsigned, f);
  u += 0x7fff + ((u >> 16) & 1);
  return (short)(u >> 16);
}

// PV matmul: 16x16x16 bf16 MFMA. Builtin probe device-side only (host pass
// can't see amdgcn builtins — R3 lesson).
__device__ __forceinline__ float4v mfma_pv(short4v a, short4v b, float4v c) {
#if defined(__HIP_DEVICE_COMPILE__)
#if __has_builtin(__builtin_amdgcn_mfma_f32_16x16x16_bf16)
  return __builtin_amdgcn_mfma_f32_16x16x16_bf16(a, b, c, 0, 0, 0);
#else
  return __builtin_amdgcn_mfma_f32_16x16x16bf16_1k(a, b, c, 0, 0, 0);
#endif
#else
  (void)a; (void)b;
  return c;
#endif
}

// ---------------------------------------------------------------------------
// Convert query/key f32 -> bf16 into d_out (free scratch until flash writes).
// ---------------------------------------------------------------------------
__global__ __launch_bounds__(256) void convert_qk(const float* __restrict__ q,
                                                  const float* __restrict__ k,
                                                  short* __restrict__ dst0)
{
  const float* src = blockIdx.y ? k : q;
  short* dst = dst0 + (size_t)blockIdx.y * 8388608;
  const size_t base = ((size_t)blockIdx.x * 256 + threadIdx.x) * 8;
  float4v a = *(const float4v*)&src[base];
  float4v b = *(const float4v*)&src[base + 4];
  short8 o8 = {f2bf(a.x), f2bf(a.y), f2bf(a.z), f2bf(a.w),
               f2bf(b.x), f2bf(b.y), f2bf(b.z), f2bf(b.w)};
  *(short8*)&dst[base] = o8;
}

// Convert Wq/Wk/Wv f32 -> bf16 into ws (enables async-LDS B staging)
__global__ __launch_bounds__(256) void convert_w(const float* __restrict__ Wq,
                                                 const float* __restrict__ Wk,
                                                 const float* __restrict__ Wv,
                                                 short* __restrict__ Wbf)
{
  const int z = blockIdx.y;
  const float* src = (z == 0) ? Wq : (z == 1) ? Wk : Wv;
  short* dst = Wbf + (size_t)z * 1048576;
  const size_t base = ((size_t)blockIdx.x * 256 + threadIdx.x) * 8;
  float4v a = *(const float4v*)&src[base];
  float4v b = *(const float4v*)&src[base + 4];
  short8 o8 = {f2bf(a.x), f2bf(a.y), f2bf(a.z), f2bf(a.w),
               f2bf(b.x), f2bf(b.y), f2bf(b.z), f2bf(b.w)};
  *(short8*)&dst[base] = o8;
}

// ---------------------------------------------------------------------------
// GEMM R7: out = A @ W^T, BK=64 (two 32-col planes), XCD-aware 1D swizzle.
// b&7 = XCD (dispatch round-robin heuristic); within an XCD, y varies
// fastest over a fixed x-tile -> the XCD's working set = one 256 KB A-tile
// + 2 MiB of W, both L2-resident; A partitioned across XCDs (no cross-XCD
// A duplication). z=0: Q (scaled log2e/32 for exp2 flash), z=1: K,
// z=2: V stored transposed Vt[n][d][kpos].
// ---------------------------------------------------------------------------
template <bool WBF>
__global__ __launch_bounds__(256, 2) void gemm_qkv(
    const short* __restrict__ Abf, const float* __restrict__ Wq,
    const float* __restrict__ Wk, const float* __restrict__ Wv,
    const short* __restrict__ Wbf,
    short* __restrict__ Qbf, short* __restrict__ Kbf, short* __restrict__ Vt)
{
  __shared__ __align__(16) short As[2 * 4096];  // [plane(2)][128 rows][32]
  __shared__ __align__(16) short Bs[2 * 4096];

  // swizzle: xcd = b&7; w = b>>3: y = w&7 (fastest), xl = (w>>3)&7, z = w>>6
  const int b = blockIdx.x;
  const int xcd = b & 7;
  const int w = b >> 3;
  const int z = w >> 6;                     // 0..2
  const int m0 = (((w >> 3) & 7) | (xcd << 3)) * 128;
  const int n0 = (w & 7) * 128;

  const short* Ag = (z == 0) ? Abf : (Abf + 8388608);
  const float* Wg = (z == 0) ? Wq : (z == 1) ? Wk : Wv;
  const short* Wbz = WBF ? (Wbf + (size_t)z * 1048576) : nullptr;

  const int t = threadIdx.x;
  const int lane = t & 63;
  const int lrow = lane & 15;
  const int quad = lane >> 4;
  const int wave = t >> 6;
  const int wm = (wave & 1) * 64;
  const int wn = (wave >> 1) * 64;

  // staging indices: chunk (q*256+t) -> row = q*64 + (t>>2), col8 = (t&3)*8
  const int srow = t >> 2;
  const int scol8 = (t & 3) * 8;

  float4v acc[4][4];
#pragma unroll
  for (int i = 0; i < 4; i++)
#pragma unroll
    for (int j = 0; j < 4; j++) acc[i][j] = (float4v){0.f, 0.f, 0.f, 0.f};

  for (int kk = 0; kk < 1024; kk += 64) {
    __syncthreads();
#pragma unroll
    for (int pl = 0; pl < 2; pl++) {
#pragma unroll
      for (int q = 0; q < 2; q++) {
        const int row = q * 64 + srow;
        const short* gp = &Ag[(size_t)(m0 + row) * DM + kk + pl * 32 + scol8];
        short* lp = &As[pl * 4096 + (q * 256 + (t & 192)) * 8];
        __builtin_amdgcn_global_load_lds((const GAS void*)gp, (LAS void*)lp, 16, 0, 0);
        if (WBF) {
          const short* gpb = &Wbz[(size_t)(n0 + row) * DM + kk + pl * 32 + scol8];
          short* lpb = &Bs[pl * 4096 + (q * 256 + (t & 192)) * 8];
          __builtin_amdgcn_global_load_lds((const GAS void*)gpb, (LAS void*)lpb, 16, 0, 0);
        }
      }
    }
    if (!WBF) {
#pragma unroll
      for (int p = 0; p < 4; p++) {
        const int row = p * 32 + (t >> 3);
#pragma unroll
        for (int cp = 0; cp < 2; cp++) {
          const int c4 = (t & 7) * 4;
          float4v bb = *(const float4v*)&Wg[(size_t)(n0 + row) * DM + kk + cp * 32 + c4];
          short4v b16 = {f2bf(bb.x), f2bf(bb.y), f2bf(bb.z), f2bf(bb.w)};
          *(short4v*)&Bs[cp * 4096 + row * 32 + c4] = b16;
        }
      }
    }
    __syncthreads();

#pragma unroll
    for (int ko = 0; ko < 2; ko++) {
      short8 af[4], bf[4];
#pragma unroll
      for (int i = 0; i < 4; i++) {
        af[i] = *(const short8*)&As[ko * 4096 + (wm + i * 16 + lrow) * 32 + quad * 8];
        bf[i] = *(const short8*)&Bs[ko * 4096 + (wn + i * 16 + lrow) * 32 + quad * 8];
      }
#pragma unroll
      for (int i = 0; i < 4; i++)
#pragma unroll
        for (int j = 0; j < 4; j++)
          acc[i][j] = __builtin_amdgcn_mfma_f32_16x16x32_bf16(af[i], bf[j],
                                                              acc[i][j], 0, 0, 0);
    }
  }

  if (z < 2) {
    short* Og = (z == 0) ? Qbf : Kbf;
    // Q scale: 1/sqrt(D) * log2(e) so flash uses exp2 directly
    const float sc = (z == 0) ? 0.03125f * 1.44269504f : 1.0f;
#pragma unroll
    for (int i = 0; i < 4; i++)
#pragma unroll
      for (int j = 0; j < 4; j++)
#pragma unroll
        for (int r = 0; r < 4; r++) {
          const int row = m0 + wm + i * 16 + quad * 4 + r;
          const int col = n0 + wn + j * 16 + lrow;
          Og[(size_t)row * DM + col] = f2bf(acc[i][j][r] * sc);
        }
  } else {
#pragma unroll
    for (int i = 0; i < 4; i++) {
      const int rowb = m0 + wm + i * 16 + quad * 4;
      const int batch = rowb >> 11;
      const int kpos = rowb & 2047;
#pragma unroll
      for (int j = 0; j < 4; j++) {
        const int col = n0 + wn + j * 16 + lrow;
        short4v pk = {f2bf(acc[i][j][0]), f2bf(acc[i][j][1]),
                      f2bf(acc[i][j][2]), f2bf(acc[i][j][3])};
        *(short4v*)&Vt[(size_t)batch * DM * LQN + (size_t)col * LQN + kpos] = pk;
      }
    }
  }
}

// ---------------------------------------------------------------------------
// Flash attention R7: R5 structure (1024 blocks, 4/CU residency — R6 proved
// 2/CU starves the latency chain) + per-CU qt balancing. Under round-robin
// dispatch, blocks {u, u+256, u+512, u+768} share a CU; their qts are
// {a, 15-a, a+4, 11-a} (a = u>>6) -> per-CU nkt sum = 68, uniform, and a
// perfect partition of qt=0..15. Same-(n,h) blocks stay ≡ mod 8 -> XCD KV
// L2 locality. Worst case (dispatch differs) degrades to R5's imbalance.
// Per tile: 4 waves x 32 q-rows, 64-key double-buffered LDS (K async
// global_load_lds, V reg-load-early/ds_write-late), one barrier/iter,
// S^T = K*Q^T keeps P in registers, exp2 (log2e folded into Q).
// ---------------------------------------------------------------------------
__global__ __launch_bounds__(256, 4) void flash_attn(
    const short* __restrict__ Qbf, const short* __restrict__ Kbf,
    const short* __restrict__ Vt, const float* __restrict__ query,
    float* __restrict__ res)
{
  __shared__ __align__(16) short Ks[2][4096];     // [dh(2)][key(64)][32 d]
  __shared__ __align__(16) short Vs[2][64 * 76];  // [d(64)][76: 64 keys+pad]

  const int b = blockIdx.x;       // 0..1023
  const int slot = b >> 8;        // CU-slot under round-robin dispatch
  const int u = b & 255;
  const int nh = u & 63;
  const int a = u >> 6;           // 0..3
  const int qt = (slot == 0) ? a : (slot == 1) ? (15 - a)
               : (slot == 2) ? (a + 4) : (11 - a);
  const int h = nh & 15;
  const int n = nh >> 4;
  const int t = threadIdx.x;
  const int lane = t & 63;
  const int wave = t >> 6;
  const int lrow = lane & 15;
  const int quad = lane >> 4;

  const size_t rowoff = (size_t)n * LQN;
  const size_t hcol = (size_t)h * 64;
  const size_t vtoff = (size_t)n * (size_t)DM * LQN + hcol * LQN;

  const int qb = qt * 128;
  const int wrow = qb + wave * 32;  // wave's first q-row

  // Q fragments [mt][dhalf] (B-operand of S^T)
  short8 qf[2][2];
#pragma unroll
  for (int mt = 0; mt < 2; mt++)
#pragma unroll
    for (int dh = 0; dh < 2; dh++)
      qf[mt][dh] = *(const short8*)
          &Qbf[(rowoff + wrow + mt * 16 + lrow) * DM + hcol + dh * 32 + quad * 8];

  float4v o[2][4];
#pragma unroll
  for (int mt = 0; mt < 2; mt++)
#pragma unroll
    for (int j = 0; j < 4; j++) o[mt][j] = (float4v){0.f, 0.f, 0.f, 0.f};
  float lsum[2] = {0.f, 0.f};

  const int nkt = 2 * qt + 2;

  // staging indices
  const int skey = t >> 2;            // K: key row / V: d row
  const int sq8 = (t & 3) * 8;        // K: d-offset
  const int skq = (t & 3) * 16;       // V: key-offset
  const int ldsbase = (t & 192) * 8;  // wave-uniform (HW adds lane*16B)

  // prologue: stage tile 0
  {
    const short* g0 = &Kbf[(rowoff + skey) * DM + hcol + sq8];
    __builtin_amdgcn_global_load_lds((const GAS void*)g0,
                                     (LAS void*)&Ks[0][ldsbase], 16, 0, 0);
    const short* g1 = &Kbf[(rowoff + skey) * DM + hcol + 32 + sq8];
    __builtin_amdgcn_global_load_lds((const GAS void*)g1,
                                     (LAS void*)&Ks[0][2048 + ldsbase], 16, 0, 0);
    const short* gv = &Vt[vtoff + (size_t)skey * LQN + skq];
    short4v v0 = *(const short4v*)(gv);
    short4v v1 = *(const short4v*)(gv + 4);
    short4v v2 = *(const short4v*)(gv + 8);
    short4v v3 = *(const short4v*)(gv + 12);
    short* l = &Vs[0][skey * 76 + skq];
    *(short4v*)(l + 0) = v0;
    *(short4v*)(l + 4) = v1;
    *(short4v*)(l + 8) = v2;
    *(short4v*)(l + 12) = v3;
  }

  for (int kt = 0; kt < nkt; kt++) {
    __syncthreads();  // drains async K + makes V writes visible
    const int buf = kt & 1;
    const int nbuf = buf ^ 1;
    const int kbase = kt * 64;
    const bool more = (kt + 1 < nkt);

    short4v v0, v1, v2, v3;
    if (more) {  // issue next tile's loads NOW
      const int kb2 = kbase + 64;
      const short* g0 = &Kbf[(rowoff + kb2 + skey) * DM + hcol + sq8];
      __builtin_amdgcn_global_load_lds((const GAS void*)g0,
                                       (LAS void*)&Ks[nbuf][ldsbase], 16, 0, 0);
      const short* g1 = &Kbf[(rowoff + kb2 + skey) * DM + hcol + 32 + sq8];
      __builtin_amdgcn_global_load_lds((const GAS void*)g1,
                                       (LAS void*)&Ks[nbuf][2048 + ldsbase], 16, 0, 0);
      const short* gv = &Vt[vtoff + (size_t)skey * LQN + kb2 + skq];
      v0 = *(const short4v*)(gv);
      v1 = *(const short4v*)(gv + 4);
      v2 = *(const short4v*)(gv + 8);
      v3 = *(const short4v*)(gv + 12);
    }

    const int drel = wrow - kbase;
#pragma unroll
    for (int f4 = 0; f4 < 4; f4++) {
      if (f4 * 16 > drel + 31) continue;  // fully masked both mt (uniform)
      short8 kf0 = *(const short8*)&Ks[buf][(f4 * 16 + lrow) * 32 + quad * 8];
      short8 kf1 = *(const short8*)&Ks[buf][2048 + (f4 * 16 + lrow) * 32 + quad * 8];
      short4v vf[4];
#pragma unroll
      for (int j = 0; j < 4; j++)
        vf[j] = *(const short4v*)&Vs[buf][(j * 16 + lrow) * 76 + f4 * 16 + quad * 4];
#pragma unroll
      for (int mt = 0; mt < 2; mt++) {
        if (f4 * 16 > drel + mt * 16 + 15) continue;  // fully masked (uniform)
        float4v z = (float4v){0.f, 0.f, 0.f, 0.f};
        z = __builtin_amdgcn_mfma_f32_16x16x32_bf16(kf0, qf[mt][0], z, 0, 0, 0);
        z = __builtin_amdgcn_mfma_f32_16x16x32_bf16(kf1, qf[mt][1], z, 0, 0, 0);
        const bool pm = (f4 * 16 + 15 > drel + mt * 16);  // partial mask?
        const int dk = drel + mt * 16 + lrow;
        short4v pk;
        float ls = 0.f;
#pragma unroll
        for (int r = 0; r < 4; r++) {
          float p = exp2f(z[r]);  // log2e/32 folded into Q; |s| small, no max
          if (pm && (f4 * 16 + quad * 4 + r > dk)) p = 0.f;
          ls += p;
          pk[r] = f2bf(p);
        }
        lsum[mt] += ls;
#pragma unroll
        for (int j = 0; j < 4; j++)
          o[mt][j] = mfma_pv(pk, vf[j], o[mt][j]);
      }
    }

    if (more) {  // ds_write AFTER compute: vmcnt wait lands post-compute
      short* l = &Vs[nbuf][skey * 76 + skq];
      *(short4v*)(l + 0) = v0;
      *(short4v*)(l + 4) = v1;
      *(short4v*)(l + 8) = v2;
      *(short4v*)(l + 12) = v3;
    }
  }

  // column sums: reduce across quads, then fetch per-C/D-row inverse
  float inv[2][4];
#pragma unroll
  for (int mt = 0; mt < 2; mt++) {
    float s = lsum[mt];
    s += __shfl_xor(s, 16);
    s += __shfl_xor(s, 32);
#pragma unroll
    for (int r = 0; r < 4; r++) inv[mt][r] = 1.0f / __shfl(s, quad * 4 + r);
  }

  // res = O/l + query
#pragma unroll
  for (int mt = 0; mt < 2; mt++)
#pragma unroll
    for (int r = 0; r < 4; r++) {
      const size_t row = rowoff + wrow + mt * 16 + quad * 4 + r;
#pragma unroll
      for (int j = 0; j < 4; j++) {
        const size_t idx = row * DM + hcol + j * 16 + lrow;
        res[idx] = o[mt][j][r] * inv[mt][r] + query[idx];
      }
    }
}

// ---------------------------------------------------------------------------
// BatchNorm over (8192, 1024)
// ---------------------------------------------------------------------------
__global__ __launch_bounds__(256) void bn_stats(const float* __restrict__ res,
                                                float* __restrict__ stats)
{
  const int t = threadIdx.x;
  const int b = blockIdx.x;  // 512 blocks x 16 rows
  float4v sum = (float4v){0.f, 0.f, 0.f, 0.f};
  float4v sq = (float4v){0.f, 0.f, 0.f, 0.f};
  for (int r = 0; r < 16; r++) {
    float4v v = *(const float4v*)&res[(size_t)(b * 16 + r) * DM + t * 4];
    sum += v;
    sq += v * v;
  }
#pragma unroll
  for (int i = 0; i < 4; i++) {
    atomicAdd(&stats[t * 4 + i], sum[i]);
    atomicAdd(&stats[1024 + t * 4 + i], sq[i]);
  }
}

__global__ __launch_bounds__(256) void bn_apply(float* __restrict__ res,
                                                const float* __restrict__ stats,
                                                const float* __restrict__ gamma,
                                                const float* __restrict__ beta)
{
  const size_t i = (size_t)blockIdx.x * 256 + threadIdx.x;
  const int c = (int)(i & 255) * 4;
  float4v v = *(const float4v*)&res[i * 4];
  float4v sm = *(const float4v*)&stats[c];
  float4v sq = *(const float4v*)&stats[1024 + c];
  float4v g = *(const float4v*)&gamma[c];
  float4v bt = *(const float4v*)&beta[c];
  float4v outv;
#pragma unroll
  for (int j = 0; j < 4; j++) {
    const float mean = sm[j] * (1.0f / 8192.0f);
    const float var = sq[j] * (1.0f / 8192.0f) - mean * mean;
    outv[j] = (v[j] - mean) * rsqrtf(var + 1e-5f) * g[j] + bt[j];
  }
  *(float4v*)&res[i * 4] = outv;
}

// ---------------------------------------------------------------------------
extern "C" void kernel_launch(void* const* d_in, const int* in_sizes, int n_in,
                              void* d_out, int out_size, void* d_ws,
                              size_t ws_size, hipStream_t stream)
{
  const float* query = (const float*)d_in[0];
  const float* key   = (const float*)d_in[1];
  const float* Wq    = (const float*)d_in[2];
  const float* Wk    = (const float*)d_in[3];
  const float* Wv    = (const float*)d_in[4];
  const float* gamma = (const float*)d_in[5];
  const float* beta  = (const float*)d_in[6];
  float* out = (float*)d_out;

  char* ws = (char*)d_ws;
  short* Qbf = (short*)(ws);                               // 16 MiB
  short* Kbf = (short*)(ws + (size_t)16 * 1024 * 1024);    // 16 MiB
  short* Vt  = (short*)(ws + (size_t)32 * 1024 * 1024);    // 16 MiB (V^T)
  float* stats = (float*)(ws + (size_t)48 * 1024 * 1024);  // 8 KiB
  short* Wbf = (short*)(ws + (size_t)49 * 1024 * 1024);    // 6 MiB (optional)
  const bool wbf = ws_size >= ((size_t)55 << 20);

  (void)hipMemsetAsync(stats, 0, 2048 * sizeof(float), stream);

  convert_qk<<<dim3(4096, 2), 256, 0, stream>>>(query, key, (short*)d_out);
  if (wbf) {
    convert_w<<<dim3(512, 3), 256, 0, stream>>>(Wq, Wk, Wv, Wbf);
    gemm_qkv<true><<<dim3(1536), 256, 0, stream>>>(
        (const short*)d_out, Wq, Wk, Wv, Wbf, Qbf, Kbf, Vt);
  } else {
    gemm_qkv<false><<<dim3(1536), 256, 0, stream>>>(
        (const short*)d_out, Wq, Wk, Wv, nullptr, Qbf, Kbf, Vt);
  }
  flash_attn<<<dim3(1024), 256, 0, stream>>>(Qbf, Kbf, Vt, query, out);
  bn_stats<<<dim3(512), 256, 0, stream>>>(out, stats);
  bn_apply<<<dim3(8192), 256, 0, stream>>>(out, stats, gamma, beta);
}